// Round 1
// 126.770 us; speedup vs baseline: 1.0044x; 1.0044x over previous
//
#include <hip/hip_runtime.h>

// lambda-return reverse scan, T=16 rows x B=524288 cols, fp32.
//
// v2 strategy: ROLLING 4-row software pipeline instead of full 46-load flood.
// Theory: the previous full-register-prefetch issued all 46 loads (spread over
// 46 x 2MiB-strided rows) at wave start; 4096 waves doing this simultaneously
// scatter requests over the whole 126 MB working set -> DRAM row-buffer
// thrash -> ~45% HBM efficiency (~2.9 TB/s, kernel ~44us vs ~20us roofline).
// Rolling window keeps all waves phase-locked marching rows 14->0, so the
// instantaneous read footprint is ~3 contiguous 2MiB row segments.
//
// __launch_bounds__(256, 8): the 2nd arg (8 waves/EU) caps VGPRs at 64 --
// this is the anti-flood enforcement: compiler cannot re-hoist loads into a
// window wider than ~5 rows. Occupancy itself is grid-capped at 16 waves/CU
// regardless (1024 blocks x 4 waves / 256 CUs).
// In-flight per CU: 16 waves x ~12 loads x 512 B ~= 98 KB >> ~10 KB needed.

constexpr int   T_STEPS = 16;
constexpr float LAM     = 0.95f;
constexpr int   W       = 4;   // rows in flight (ring buffer, power of 2)

__global__ __launch_bounds__(256, 8)
void ImagBehavior_67284957659345_kernel(const float2* __restrict__ reward,
                                        const float2* __restrict__ value,
                                        const float2* __restrict__ discount,
                                        float2* __restrict__ out,
                                        int Bv /* = B/2 */) {
    int idx = blockIdx.x * blockDim.x + threadIdx.x;
    if (idx >= Bv) return;

    float2 r[W], d[W], v[W];

    // bootstrap: acc = value[15]
    float2 acc = value[(T_STEPS - 1) * Bv + idx];

    // prologue: issue rows 14,13,12,11 (r,d,v each)
#pragma unroll
    for (int j = 0; j < W; ++j) {
        const int t = T_STEPS - 2 - j;  // 14..11
        r[t & (W - 1)] = reward[t * Bv + idx];
        d[t & (W - 1)] = discount[t * Bv + idx];
        v[t & (W - 1)] = value[t * Bv + idx];
    }

    float2 v_next = acc;  // v[t+1] for step t=14 is v[15] == bootstrap

#pragma unroll
    for (int t = T_STEPS - 2; t >= 0; --t) {
        const int s = t & (W - 1);
        // grab row-t data out of the ring BEFORE slot s is re-issued below
        const float2 rt    = r[s];
        const float2 dt    = d[s];
        const float2 vt1   = v_next;  // v[t+1]
        const float2 vtcur = v[s];    // v[t], needed at step t-1

        // steady-state issue: row t-W into the slot we just freed.
        // Issued BEFORE the vmcnt wait for row t's data -> stays in flight
        // across the compute+store of this step.
        const int tp = t - W;
        if (tp >= 0) {
            r[tp & (W - 1)] = reward[tp * Bv + idx];
            d[tp & (W - 1)] = discount[tp * Bv + idx];
            if (tp >= 1) v[tp & (W - 1)] = value[tp * Bv + idx];  // v[0] never read
        }

        // serial chain -- expression order identical to v1 (bitwise-same absmax)
        acc.x = rt.x + dt.x * (LAM * acc.x + (1.0f - LAM) * vt1.x);
        acc.y = rt.y + dt.y * (LAM * acc.y + (1.0f - LAM) * vt1.y);
        out[t * Bv + idx] = acc;  // fire-and-forget store

        v_next = vtcur;
    }
}

extern "C" void kernel_launch(void* const* d_in, const int* in_sizes, int n_in,
                              void* d_out, int out_size, void* d_ws, size_t ws_size,
                              hipStream_t stream) {
    const float2* reward   = (const float2*)d_in[0];
    const float2* value    = (const float2*)d_in[1];
    const float2* discount = (const float2*)d_in[2];
    float2*       out      = (float2*)d_out;

    const int B  = in_sizes[0] / T_STEPS;  // 524288
    const int Bv = B / 2;                  // 262144 float2 columns

    const int block = 256;
    const int grid  = (Bv + block - 1) / block;  // 1024 blocks

    ImagBehavior_67284957659345_kernel<<<grid, block, 0, stream>>>(
        reward, value, discount, out, Bv);
}